// Round 1
// baseline (206.029 us; speedup 1.0000x reference)
//
#include <hip/hip_runtime.h>
#include <hip/hip_bf16.h>

typedef __attribute__((ext_vector_type(8))) short v8s;   // 8 x bf16 (4 VGPRs)
typedef __attribute__((ext_vector_type(4))) float v4f;   // MFMA accumulator

typedef const __attribute__((address_space(1))) void* gas_ptr;
typedef __attribute__((address_space(3))) void* las_ptr;

#define MFMA16(a, b, c) __builtin_amdgcn_mfma_f32_16x16x32_bf16((a), (b), (c), 0, 0, 0)

__device__ __forceinline__ void gload_lds16(const void* g, void* l) {
  __builtin_amdgcn_global_load_lds((gas_ptr)g, (las_ptr)l, 16, 0, 0);
}

__device__ __forceinline__ unsigned short f2bf(float f) {
  unsigned int u = __float_as_uint(f);
  u += 0x7FFFu + ((u >> 16) & 1u);   // RNE
  return (unsigned short)(u >> 16);
}
__device__ __forceinline__ float bf2f(unsigned short h) {
  return __uint_as_float(((unsigned int)h) << 16);
}

// ---------------- kernel 1: fp32 -> bf16 straight convert ----------------
__global__ __launch_bounds__(256) void k_convert(const float* __restrict__ in,
                                                 unsigned short* __restrict__ out, int n4) {
  int i = blockIdx.x * 256 + threadIdx.x;
  if (i >= n4) return;
  float4 v = ((const float4*)in)[i];
  ushort4 o;
  o.x = f2bf(v.x); o.y = f2bf(v.y); o.z = f2bf(v.z); o.w = f2bf(v.w);
  ((ushort4*)out)[i] = o;
}

// ------------- kernel 2: fp32 [R][C] -> bf16 [C][R] (transpose) -----------
__global__ __launch_bounds__(256) void k_transpose_convert(const float* __restrict__ in,
                                                           unsigned short* __restrict__ out,
                                                           int R, int C) {
  __shared__ __attribute__((aligned(16))) unsigned short tb[64 * 72];
  const int r0 = blockIdx.y * 64, c0 = blockIdx.x * 64;
  const int tid = threadIdx.x;
#pragma unroll
  for (int j = 0; j < 4; ++j) {
    int slot = tid + 256 * j;
    int row = slot >> 4, q4 = (slot & 15) * 4;
    float4 v = *(const float4*)&in[(size_t)(r0 + row) * C + c0 + q4];
    ushort4 o;
    o.x = f2bf(v.x); o.y = f2bf(v.y); o.z = f2bf(v.z); o.w = f2bf(v.w);
    *(ushort4*)&tb[row * 72 + q4] = o;
  }
  __syncthreads();
#pragma unroll
  for (int j = 0; j < 4; ++j) {
    int slot = tid + 256 * j;
    int crow = slot >> 4, t4 = (slot & 15) * 4;
    ushort4 o;
    o.x = tb[(t4 + 0) * 72 + crow];
    o.y = tb[(t4 + 1) * 72 + crow];
    o.z = tb[(t4 + 2) * 72 + crow];
    o.w = tb[(t4 + 3) * 72 + crow];
    *(ushort4*)&out[(size_t)(c0 + crow) * R + r0 + t4] = o;
  }
}

// ---------------- kernel 3: bf16 GEMM, m97 structure ----------------------
// A: [M][K] row-major bf16.  Bt: [N][K] row-major bf16 (i.e. B^T).
// C = A @ B. F32OUT ? fp32 out : bf16 out.
template <bool F32OUT>
__global__ __launch_bounds__(256) void k_gemm(const unsigned short* __restrict__ A,
                                              const unsigned short* __restrict__ Bt,
                                              void* __restrict__ Cout,
                                              int M, int N, int K) {
  __shared__ __attribute__((aligned(16))) unsigned short As[128 * 32];
  __shared__ __attribute__((aligned(16))) unsigned short Bs[128 * 32];
  const int tid = threadIdx.x;
  const int w = tid >> 6, l = tid & 63, g = l >> 4, c = l & 15;
  const int wr = w >> 1, wc = w & 1;
  const int mt = blockIdx.y * 128, nt = blockIdx.x * 128;
  const int rowc = l >> 2, kslot = (l & 3) * 8;

  v4f acc[4][4];
#pragma unroll
  for (int m = 0; m < 4; ++m)
#pragma unroll
    for (int n = 0; n < 4; ++n) acc[m][n] = (v4f){0.f, 0.f, 0.f, 0.f};

  for (int kt = 0; kt < K; kt += 32) {
    __syncthreads();
#pragma unroll
    for (int i = 0; i < 2; ++i) {
      int ch = w + 4 * i;  // 16-row chunk
      gload_lds16(&A[(size_t)(mt + ch * 16 + rowc) * K + kt + kslot], &As[ch * 512]);
      gload_lds16(&Bt[(size_t)(nt + ch * 16 + rowc) * K + kt + kslot], &Bs[ch * 512]);
    }
    __syncthreads();
    v8s af[4], bfr[4];
#pragma unroll
    for (int m = 0; m < 4; ++m)
      af[m] = *(const v8s*)&As[(wr * 64 + m * 16 + c) * 32 + g * 8];
#pragma unroll
    for (int n = 0; n < 4; ++n)
      bfr[n] = *(const v8s*)&Bs[(wc * 64 + n * 16 + c) * 32 + g * 8];
#pragma unroll
    for (int m = 0; m < 4; ++m)
#pragma unroll
      for (int n = 0; n < 4; ++n)
        acc[m][n] = MFMA16(af[m], bfr[n], acc[m][n]);
  }

#pragma unroll
  for (int m = 0; m < 4; ++m)
#pragma unroll
    for (int n = 0; n < 4; ++n)
#pragma unroll
      for (int r = 0; r < 4; ++r) {
        int row = mt + wr * 64 + m * 16 + g * 4 + r;
        int col = nt + wc * 64 + n * 16 + c;
        if (F32OUT)
          ((float*)Cout)[(size_t)row * N + col] = acc[m][n][r];
        else
          ((unsigned short*)Cout)[(size_t)row * N + col] = f2bf(acc[m][n][r]);
      }
}

// ------- kernel 4: qkv [4096][3072] -> q,k roped (B,H,T,D) + v^T (B,H,D,T) -------
__global__ __launch_bounds__(256) void k_post(const unsigned short* __restrict__ qkv,
                                              unsigned short* __restrict__ qb,
                                              unsigned short* __restrict__ kb,
                                              unsigned short* __restrict__ vT) {
  __shared__ float2 cs[64 * 32];                                  // cos/sin per (t_local, i)
  __shared__ __attribute__((aligned(16))) unsigned short vt[64 * 72];
  const int bh = blockIdx.y;
  const int b = bh >> 4, h = bh & 15;
  const int t0 = blockIdx.x * 64;
  const int tid = threadIdx.x;

  // phase 0: rope table for this 64-row slab
#pragma unroll
  for (int e = 0; e < 8; ++e) {
    int idx = tid + 256 * e;  // = tl*32 + i
    int tl = idx >> 5, i = idx & 31;
    float invf = exp2f(-(float)i * 0.41524101186092034f);  // 10000^(-i/32)
    float ang = (float)(t0 + tl) * invf;
    float s, cc;
    sincosf(ang, &s, &cc);
    cs[idx] = make_float2(cc, s);
  }
  // phase 0b: stage V tile
#pragma unroll
  for (int j = 0; j < 2; ++j) {
    int slot = tid + 256 * j;
    int row = slot >> 3, c8 = (slot & 7) * 8;
    v8s vv = *(const v8s*)&qkv[(size_t)(b * 2048 + t0 + row) * 3072 + 2048 + h * 64 + c8];
    *(v8s*)&vt[row * 72 + c8] = vv;
  }
  __syncthreads();

  // phase 1: rope q and k, write (B,H,T,D)
#pragma unroll
  for (int j = 0; j < 2; ++j) {
    int slot = tid + 256 * j;
    int row = slot >> 3, d0 = (slot & 7) * 8;
    int t = t0 + row;
    size_t base = (size_t)(b * 2048 + t) * 3072 + h * 64;
#pragma unroll
    for (int which = 0; which < 2; ++which) {  // 0 = q, 1 = k
      v8s vq = *(const v8s*)&qkv[base + which * 1024 + d0];
      union { unsigned short s[8]; v8s v; } uo;
#pragma unroll
      for (int p = 0; p < 4; ++p) {
        float2 sc = cs[row * 32 + d0 / 2 + p];
        float x1 = bf2f((unsigned short)vq[2 * p]);
        float x2 = bf2f((unsigned short)vq[2 * p + 1]);
        uo.s[2 * p]     = f2bf(x1 * sc.x - x2 * sc.y);
        uo.s[2 * p + 1] = f2bf(x1 * sc.y + x2 * sc.x);
      }
      unsigned short* dst = which ? kb : qb;
      *(v8s*)&dst[((size_t)bh * 2048 + t) * 64 + d0] = uo.v;
    }
  }
  // phase 2: write V^T (B,H,D,T)
#pragma unroll
  for (int j = 0; j < 2; ++j) {
    int slot = tid + 256 * j;
    int d = slot >> 3, t8 = (slot & 7) * 8;
    union { unsigned short s[8]; v8s v; } uo;
#pragma unroll
    for (int e = 0; e < 8; ++e) uo.s[e] = vt[(t8 + e) * 72 + d];
    *(v8s*)&vT[((size_t)bh * 64 + d) * 2048 + t0 + t8] = uo.v;
  }
}

// ---------------- kernel 5: causal flash attention (swapped-operand) -------------
// q,k: (B,H,T,D) bf16 roped. vT: (B,H,D,T) bf16. ao: (B*T, C) bf16.
// One wave owns 32 q-rows; computes S^T = mfma(K, Q); O^T = mfma(V^T, P^T). No LDS.
__global__ __launch_bounds__(256) void k_attn(const unsigned short* __restrict__ qb,
                                              const unsigned short* __restrict__ kb,
                                              const unsigned short* __restrict__ vT,
                                              unsigned short* __restrict__ ao) {
  const int bh = blockIdx.y;
  const int qt = 15 - (int)blockIdx.x;  // big tiles dispatch first
  const int tid = threadIdx.x;
  const int w = tid >> 6, l = tid & 63, g = l >> 4, c = l & 15;
  const int qbase = qt * 128 + w * 32;
  const unsigned short* Qp = qb + ((size_t)bh * 2048 + qbase) * 64;
  const unsigned short* Kp = kb + (size_t)bh * 2048 * 64;
  const unsigned short* Vp = vT + (size_t)bh * 64 * 2048;

  v8s bq[2][2];
#pragma unroll
  for (int nq = 0; nq < 2; ++nq)
#pragma unroll
    for (int kd = 0; kd < 2; ++kd)
      bq[nq][kd] = *(const v8s*)&Qp[(nq * 16 + c) * 64 + kd * 32 + g * 8];

  float m2[2] = {-1e30f, -1e30f};
  float ls[2] = {0.f, 0.f};
  v4f ot[4][2];
#pragma unroll
  for (int md = 0; md < 4; ++md)
#pragma unroll
    for (int nq = 0; nq < 2; ++nq) ot[md][nq] = (v4f){0.f, 0.f, 0.f, 0.f};

  const float SC = 0.125f * 1.4426950408889634f;  // 1/sqrt(D) * log2(e)
  const int ntiles = qbase / 32 + 1;
  const int llo = ((l >> 4) & 1) * 32 + c;
  const int lhi = llo + 16;
  const bool selhi = ((g >> 1) & 1) != 0;

  v8s ak[2][2];
#pragma unroll
  for (int mk = 0; mk < 2; ++mk)
#pragma unroll
    for (int kd = 0; kd < 2; ++kd)
      ak[mk][kd] = *(const v8s*)&Kp[(mk * 16 + c) * 64 + kd * 32 + g * 8];

  for (int tkv = 0; tkv < ntiles; ++tkv) {
    const int kv0 = tkv * 32;
    // V frags for current tile (issued early, consumed after softmax)
    v8s av[4];
#pragma unroll
    for (int md = 0; md < 4; ++md)
      av[md] = *(const v8s*)&Vp[(md * 16 + c) * 2048 + kv0 + g * 8];

    // S^T = K Q^T
    v4f st[2][2];
#pragma unroll
    for (int mk = 0; mk < 2; ++mk)
#pragma unroll
      for (int nq = 0; nq < 2; ++nq) st[mk][nq] = (v4f){0.f, 0.f, 0.f, 0.f};
#pragma unroll
    for (int kd = 0; kd < 2; ++kd)
#pragma unroll
      for (int mk = 0; mk < 2; ++mk)
#pragma unroll
        for (int nq = 0; nq < 2; ++nq)
          st[mk][nq] = MFMA16(ak[mk][kd], bq[nq][kd], st[mk][nq]);

    // prefetch next K tile (hides L2 latency under softmax + PV)
    if (tkv + 1 < ntiles) {
      const int kvn = kv0 + 32;
#pragma unroll
      for (int mk = 0; mk < 2; ++mk)
#pragma unroll
        for (int kd = 0; kd < 2; ++kd)
          ak[mk][kd] = *(const v8s*)&Kp[(kvn + mk * 16 + c) * 64 + kd * 32 + g * 8];
    }

    // scale + causal mask. element: kv = kv0+16mk+4g+r (row), q = qbase+16nq+c (col)
#pragma unroll
    for (int mk = 0; mk < 2; ++mk)
#pragma unroll
      for (int nq = 0; nq < 2; ++nq)
#pragma unroll
        for (int r = 0; r < 4; ++r) {
          int kv = kv0 + mk * 16 + g * 4 + r;
          int qq = qbase + nq * 16 + c;
          float v = st[mk][nq][r] * SC;
          st[mk][nq][r] = (kv <= qq) ? v : -1e30f;
        }

    // online softmax (per q-col stats, replicated across g-groups)
    unsigned int dw[2][2][2];
#pragma unroll
    for (int nq = 0; nq < 2; ++nq) {
      float pm = st[0][nq][0];
#pragma unroll
      for (int r = 1; r < 4; ++r) pm = fmaxf(pm, st[0][nq][r]);
#pragma unroll
      for (int r = 0; r < 4; ++r) pm = fmaxf(pm, st[1][nq][r]);
      pm = fmaxf(pm, __shfl_xor(pm, 16));
      pm = fmaxf(pm, __shfl_xor(pm, 32));
      float mn = fmaxf(m2[nq], pm);
      float alpha = exp2f(m2[nq] - mn);
      m2[nq] = mn;
      float rs = 0.f;
#pragma unroll
      for (int mk = 0; mk < 2; ++mk)
#pragma unroll
        for (int r = 0; r < 4; ++r) {
          float p = exp2f(st[mk][nq][r] - mn);
          st[mk][nq][r] = p;
          rs += p;
        }
      rs += __shfl_xor(rs, 16);
      rs += __shfl_xor(rs, 32);
      ls[nq] = ls[nq] * alpha + rs;
#pragma unroll
      for (int md = 0; md < 4; ++md) ot[md][nq] *= alpha;
      dw[0][nq][0] = (unsigned)f2bf(st[0][nq][0]) | ((unsigned)f2bf(st[0][nq][1]) << 16);
      dw[0][nq][1] = (unsigned)f2bf(st[0][nq][2]) | ((unsigned)f2bf(st[0][nq][3]) << 16);
      dw[1][nq][0] = (unsigned)f2bf(st[1][nq][0]) | ((unsigned)f2bf(st[1][nq][1]) << 16);
      dw[1][nq][1] = (unsigned)f2bf(st[1][nq][2]) | ((unsigned)f2bf(st[1][nq][3]) << 16);
    }

    // redistribute P^T into PV B-fragments (pure in-register shuffles), then PV
#pragma unroll
    for (int nq = 0; nq < 2; ++nq) {
      unsigned q00 = (unsigned)__shfl((int)dw[0][nq][0], llo);
      unsigned q01 = (unsigned)__shfl((int)dw[0][nq][1], llo);
      unsigned q02 = (unsigned)__shfl((int)dw[0][nq][0], lhi);
      unsigned q03 = (unsigned)__shfl((int)dw[0][nq][1], lhi);
      unsigned q10 = (unsigned)__shfl((int)dw[1][nq][0], llo);
      unsigned q11 = (unsigned)__shfl((int)dw[1][nq][1], llo);
      unsigned q12 = (unsigned)__shfl((int)dw[1][nq][0], lhi);
      unsigned q13 = (unsigned)__shfl((int)dw[1][nq][1], lhi);
      union { unsigned int u[4]; v8s v; } bb;
      bb.u[0] = selhi ? q10 : q00;
      bb.u[1] = selhi ? q11 : q01;
      bb.u[2] = selhi ? q12 : q02;
      bb.u[3] = selhi ? q13 : q03;
#pragma unroll
      for (int md = 0; md < 4; ++md)
        ot[md][nq] = MFMA16(av[md], bb.v, ot[md][nq]);
    }
  }

  // epilogue: normalize and write attn_out (B*T, C) bf16
  const int b = bh >> 4, h = bh & 15;
#pragma unroll
  for (int nq = 0; nq < 2; ++nq) {
    float inv = 1.f / ls[nq];
    int t = qbase + nq * 16 + c;
#pragma unroll
    for (int md = 0; md < 4; ++md)
#pragma unroll
      for (int r = 0; r < 4; ++r) {
        int d = md * 16 + g * 4 + r;
        ao[(size_t)(b * 2048 + t) * 1024 + h * 64 + d] = f2bf(ot[md][nq][r] * inv);
      }
  }
}

// --------------------------------- launch ---------------------------------
extern "C" void kernel_launch(void* const* d_in, const int* in_sizes, int n_in,
                              void* d_out, int out_size, void* d_ws, size_t ws_size,
                              hipStream_t stream) {
  const float* x     = (const float*)d_in[0];  // (2,2048,1024)
  const float* w_qkv = (const float*)d_in[1];  // (1024,3072)
  const float* w_out = (const float*)d_in[2];  // (1024,1024)
  float* out = (float*)d_out;

  char* ws = (char*)d_ws;
  unsigned short* xbf  = (unsigned short*)(ws);             // 8 MiB; reused as attn_out
  unsigned short* wqT  = (unsigned short*)(ws + 8388608);   // 6 MiB  [3072][1024]
  unsigned short* woT  = (unsigned short*)(ws + 14680064);  // 2 MiB  [1024][1024]
  unsigned short* qkv  = (unsigned short*)(ws + 16777216);  // 24 MiB [4096][3072]
  unsigned short* qbuf = (unsigned short*)(ws + 41943040);  // 8 MiB  (B,H,T,D)
  unsigned short* kbuf = (unsigned short*)(ws + 50331648);  // 8 MiB  (B,H,T,D)
  unsigned short* vTb  = (unsigned short*)(ws + 58720256);  // 8 MiB  (B,H,D,T)

  k_convert<<<4096, 256, 0, stream>>>(x, xbf, 1048576);
  k_transpose_convert<<<dim3(48, 16), 256, 0, stream>>>(w_qkv, wqT, 1024, 3072);
  k_transpose_convert<<<dim3(16, 16), 256, 0, stream>>>(w_out, woT, 1024, 1024);
  k_gemm<false><<<dim3(24, 32), 256, 0, stream>>>(xbf, wqT, qkv, 4096, 3072, 1024);
  k_post<<<dim3(32, 32), 256, 0, stream>>>(qkv, qbuf, kbuf, vTb);
  k_attn<<<dim3(16, 32), 256, 0, stream>>>(qbuf, kbuf, vTb, xbf /* attn_out */);
  k_gemm<true><<<dim3(8, 32), 256, 0, stream>>>(xbf, woT, (void*)out, 4096, 1024, 1024);
}